// Round 1
// 430.825 us; speedup vs baseline: 1.0214x; 1.0214x over previous
//
#include <hip/hip_runtime.h>

// =============================================================================
// QuantumContrastiveModel — mathematical reduction:
//   StronglyEntanglingLayers is a fixed 16x16 UNITARY applied to BOTH states;
//   fidelity |<U va|U vb>|^2 = (va.vb)^2 — the circuit cancels, theta unused.
//   With u = tanh(relu(x@W1+b1)@W2+b2):
//     fid = clip( (ua.ub)^2 / (max(|ua|,1e-8)*max(|ub|,1e-8))^2, 0, 1 )
//
//   R3: DRAM-granularity fix. The R2 kernel read 128B per row per K-step
//   (rows 3136B apart) -> scattered 128B slices capped the memory system at
//   ~2.5 TB/s combined (HBM 1.33 TB/s, 16.6% peak). Now: K is chunked into
//   5 chunks of 160 floats; each block reg-stages its 64 rows' 640B-contiguous
//   chunk slices into double-buffered LDS (bf16, 43KB -> 3 blocks/CU), and
//   MFMA reads A-fragments from LDS. 32 pairs/block, 8 a-rows + 8 b-rows
//   packed per A-fragment (D rows 0-7 = a, 8-15 = b).
// =============================================================================

#define KDIM   784
#define HDIM   64
#define KSTEPS 25                        // ceil(784/32); zero-padded to 800
#define W1S_ELEMS (KSTEPS * 4 * 64 * 8)  // 51200 bf16 in B-fragment order
#define W1S_BYTES (W1S_ELEMS * 2)        // 102400 bytes

typedef float  f32x4  __attribute__((ext_vector_type(4)));
typedef short  bf16x8 __attribute__((ext_vector_type(8)));

__device__ __forceinline__ unsigned short f2bf(float f) {
  unsigned u = __float_as_uint(f);
  u += 0x7fffu + ((u >> 16) & 1u);       // round-to-nearest-even
  return (unsigned short)(u >> 16);
}

__device__ __forceinline__ float bf2f(unsigned short h) {
  return __uint_as_float(((unsigned)h) << 16);
}

__device__ __forceinline__ uint2 cvt4(f32x4 v) {
  uint2 r;
  r.x = ((unsigned)f2bf(v[0])) | (((unsigned)f2bf(v[1])) << 16);
  r.y = ((unsigned)f2bf(v[2])) | (((unsigned)f2bf(v[3])) << 16);
  return r;
}

__device__ __forceinline__ float tanh_fast(float x) {
  float e = __expf(2.0f * x);
  return 1.0f - 2.0f / (e + 1.0f);       // exact limits at +-inf
}

// --- prep: W1 (784x64 f32) -> bf16 in MFMA B-fragment order, K padded to 800;
//           W2 (64x16) -> transposed (16x64) f32.  (unchanged from R2)
__global__ __launch_bounds__(256)
void prep_kernel(const float* __restrict__ W1, const float* __restrict__ W2,
                 unsigned short* __restrict__ w1s, float* __restrict__ w2t) {
  int tid = blockIdx.x * 256 + threadIdx.x;
  if (tid < W1S_ELEMS) {
    int j  = tid & 7;            // element within 8-wide fragment
    int l  = (tid >> 3) & 63;    // lane
    int st = tid >> 9;           // s*4 + t
    int s  = st >> 2;
    int t  = st & 3;
    int k  = s * 32 + (l >> 4) * 8 + j;   // B[k][n]: k = quad*8+j
    int n  = t * 16 + (l & 15);           //          n = lane&15
    float v = (k < KDIM) ? W1[k * HDIM + n] : 0.0f;
    w1s[tid] = f2bf(v);
  }
  if (tid < HDIM * 16) {
    int c = tid >> 6;            // 0..15
    int k = tid & 63;            // 0..63
    w2t[c * HDIM + k] = W2[k * 16 + c];
  }
}

// --- main: 32 pairs/block, 256 threads (4 waves x 8 pairs).
//     K chunked 5x160 floats; 640B-contiguous staging loads -> LDS bf16,
//     double-buffered. A-frag packs 8 a-rows (D rows 0-7) + 8 b-rows (8-15).
__global__ __launch_bounds__(256, 3)
void qcm_kernel(const float* __restrict__ img_a, const float* __restrict__ img_b,
                const float* __restrict__ b1,    const float* __restrict__ b2,
                const unsigned short* __restrict__ w1s,
                const float* __restrict__ w2t,
                float* __restrict__ out) {
  // 2 buffers x 64 rows x 168 bf16 (160 data + 8 pad) = 43008 B -> 3 blocks/CU
  __shared__ __attribute__((aligned(16))) unsigned short lds_s[2][64][168];

  const int tid  = threadIdx.x;
  const int wv_  = tid >> 6;      // wave 0..3  -> pairs p0 + wv_*8 .. +7
  const int lane = tid & 63;
  const int m    = lane & 15;     // A-frag row (0-7: a-pair m, 8-15: b-pair m-8)
  const int q    = lane >> 4;     // quad: A-frag k = q*8 + j
  const int p0   = blockIdx.x * 32;

  // --- staging map: flat f = tid + 256r over 64 rows x 40 x 16B (640B/row).
  //     row 0-31 = img_a pairs, 32-63 = img_b pairs. Contiguous per row.
  const float* srcr[10];
  int rowr[10], offr[10];
  #pragma unroll
  for (int r = 0; r < 10; ++r) {
    int f   = tid + r * 256;
    int row = f / 40;             // magic-mul div
    int off = f - row * 40;       // 16B units within the 640B chunk slice
    rowr[r] = row; offr[r] = off;
    const float* base = (row < 32) ? (img_a + (size_t)(p0 + row) * KDIM)
                                   : (img_b + (size_t)(p0 + row - 32) * KDIM);
    srcr[r] = base + off * 4;
  }

  const int arow = (m < 8) ? (wv_ * 8 + m) : (32 + wv_ * 8 + (m - 8));

  f32x4 acc[4];
  #pragma unroll
  for (int t = 0; t < 4; ++t)
    acc[t][0] = acc[t][1] = acc[t][2] = acc[t][3] = 0.0f;

  const int4* bwl = (const int4*)w1s + lane;
  f32x4 z4; z4[0] = z4[1] = z4[2] = z4[3] = 0.0f;

  // --- prologue: stage chunk 0 into buf 0
  {
    f32x4 stv[10];
    #pragma unroll
    for (int r = 0; r < 10; ++r) stv[r] = *(const f32x4*)srcr[r];
    #pragma unroll
    for (int r = 0; r < 10; ++r)
      *(uint2*)&lds_s[0][rowr[r]][offr[r] * 4] = cvt4(stv[r]);
  }
  __syncthreads();

  // --- main loop: 5 chunks x 5 MFMA steps
  #pragma unroll
  for (int c = 0; c < 5; ++c) {
    // 1. issue contiguous staging loads for chunk c+1 (in flight across compute;
    //    first MFMA's vmcnt drains them once per chunk — the drain IS the HBM
    //    demand, overlapped across 12 waves/CU + de-phased blocks)
    f32x4 stv[10];
    if (c < 4) {
      #pragma unroll
      for (int r = 0; r < 10; ++r) {
        // chunk 4 covers floats 640..799; real data ends at 784 (off<36).
        // Guard also prevents OOB read past the last img_b row.
        if (c == 3 && offr[r] >= 36) stv[r] = z4;
        else stv[r] = *(const f32x4*)(srcr[r] + (c + 1) * 160);
      }
    }

    // 2. compute chunk c from buf[c&1]
    #pragma unroll
    for (int sl = 0; sl < 5; ++sl) {
      const int s = c * 5 + sl;
      int4 g0 = bwl[s * 256];
      int4 g1 = bwl[s * 256 + 64];
      int4 g2 = bwl[s * 256 + 128];
      int4 g3 = bwl[s * 256 + 192];
      bf16x8 fa = *(const bf16x8*)&lds_s[c & 1][arow][sl * 32 + q * 8];
      acc[0] = __builtin_amdgcn_mfma_f32_16x16x32_bf16(fa, __builtin_bit_cast(bf16x8, g0), acc[0], 0, 0, 0);
      acc[1] = __builtin_amdgcn_mfma_f32_16x16x32_bf16(fa, __builtin_bit_cast(bf16x8, g1), acc[1], 0, 0, 0);
      acc[2] = __builtin_amdgcn_mfma_f32_16x16x32_bf16(fa, __builtin_bit_cast(bf16x8, g2), acc[2], 0, 0, 0);
      acc[3] = __builtin_amdgcn_mfma_f32_16x16x32_bf16(fa, __builtin_bit_cast(bf16x8, g3), acc[3], 0, 0, 0);
    }

    // 3. write-late: cvt + ds_write chunk c+1 into buf[(c&1)^1]
    if (c < 4) {
      #pragma unroll
      for (int r = 0; r < 10; ++r)
        *(uint2*)&lds_s[(c & 1) ^ 1][rowr[r]][offr[r] * 4] = cvt4(stv[r]);
    }
    __syncthreads();
  }

  // --- epilogue: bias + relu, park h in LDS as bf16.
  //     D layout: row = q*4+j (0-7 = a-pairs, 8-15 = b-pairs), col = t*16+m.
  unsigned short (*lds_h)[72] = (unsigned short (*)[72])&lds_s[0][0][0];
  #pragma unroll
  for (int t = 0; t < 4; ++t) {
    float bias = b1[t * 16 + m];
    #pragma unroll
    for (int j = 0; j < 4; ++j) {
      int rr   = q * 4 + j;
      int hrow = wv_ * 8 + rr + ((q >= 2) ? 24 : 0);  // a: rows 0-31, b: 32-63
      float hv = fmaxf(acc[t][j] + bias, 0.0f);
      lds_h[hrow][t * 16 + m] = f2bf(hv);
    }
  }
  __syncthreads();

  // --- phase 2: 8 threads/pair; each computes 2 of 16 z-columns for a and b
  const int p  = tid >> 3;            // local pair 0..31
  const int q8 = tid & 7;             // column group: cols {2q8, 2q8+1}
  const unsigned short* ha_row = &lds_h[p][0];
  const unsigned short* hb_row = &lds_h[32 + p][0];

  float za[2], zb[2];
  #pragma unroll
  for (int i = 0; i < 2; ++i) { za[i] = b2[q8 * 2 + i]; zb[i] = za[i]; }

  for (int k = 0; k < HDIM; k += 4) {
    uint2 ua = *(const uint2*)(ha_row + k);
    uint2 ub = *(const uint2*)(hb_row + k);
    float a0 = bf2f((unsigned short)(ua.x & 0xffff));
    float a1 = bf2f((unsigned short)(ua.x >> 16));
    float a2 = bf2f((unsigned short)(ua.y & 0xffff));
    float a3 = bf2f((unsigned short)(ua.y >> 16));
    float b0v = bf2f((unsigned short)(ub.x & 0xffff));
    float b1v = bf2f((unsigned short)(ub.x >> 16));
    float b2v = bf2f((unsigned short)(ub.y & 0xffff));
    float b3v = bf2f((unsigned short)(ub.y >> 16));
    #pragma unroll
    for (int i = 0; i < 2; ++i) {
      f32x4 wv = *(const f32x4*)(w2t + (q8 * 2 + i) * HDIM + k);
      za[i] += a0 * wv[0] + a1 * wv[1] + a2 * wv[2] + a3 * wv[3];
      zb[i] += b0v * wv[0] + b1v * wv[1] + b2v * wv[2] + b3v * wv[3];
    }
  }

  float d = 0.0f, na2 = 0.0f, nb2 = 0.0f;
  #pragma unroll
  for (int i = 0; i < 2; ++i) {
    float ua = tanh_fast(za[i]);
    float ub = tanh_fast(zb[i]);
    d   += ua * ub;
    na2 += ua * ua;
    nb2 += ub * ub;
  }
  d   += __shfl_xor(d, 1);   d   += __shfl_xor(d, 2);   d   += __shfl_xor(d, 4);
  na2 += __shfl_xor(na2, 1); na2 += __shfl_xor(na2, 2); na2 += __shfl_xor(na2, 4);
  nb2 += __shfl_xor(nb2, 1); nb2 += __shfl_xor(nb2, 2); nb2 += __shfl_xor(nb2, 4);

  if (q8 == 0) {
    float den = fmaxf(sqrtf(na2), 1e-8f) * fmaxf(sqrtf(nb2), 1e-8f);
    float ov  = d / den;
    float fid = ov * ov;
    out[blockIdx.x * 32 + p] = fminf(fid, 1.0f);
  }
}

extern "C" void kernel_launch(void* const* d_in, const int* in_sizes, int n_in,
                              void* d_out, int out_size, void* d_ws, size_t ws_size,
                              hipStream_t stream) {
  const float* img_a = (const float*)d_in[0];
  const float* img_b = (const float*)d_in[1];
  const float* W1    = (const float*)d_in[2];
  const float* b1    = (const float*)d_in[3];
  const float* W2    = (const float*)d_in[4];
  const float* b2    = (const float*)d_in[5];
  // d_in[6] = theta: unused — the circuit is unitary, fidelity is invariant.

  unsigned short* w1s = (unsigned short*)d_ws;
  float* w2t = (float*)((char*)d_ws + W1S_BYTES);

  prep_kernel<<<(W1S_ELEMS + 255) / 256, 256, 0, stream>>>(W1, W2, w1s, w2t);

  const int n_pairs = out_size;              // 65536
  qcm_kernel<<<n_pairs / 32, 256, 0, stream>>>(img_a, img_b, b1, b2, w1s, w2t,
                                               (float*)d_out);
}

// Round 2
// 422.663 us; speedup vs baseline: 1.0411x; 1.0193x over previous
//
#include <hip/hip_runtime.h>

// =============================================================================
// QuantumContrastiveModel — mathematical reduction:
//   StronglyEntanglingLayers is a fixed 16x16 UNITARY applied to BOTH states;
//   fidelity |<U va|U vb>|^2 = (va.vb)^2 — the circuit cancels, theta unused.
//   With u = tanh(relu(x@W1+b1)@W2+b2):
//     fid = clip( (ua.ub)^2 / (max(|ua|,1e-8)*max(|ub|,1e-8))^2, 0, 1 )
//
//   R4: LINEAR-STREAM staging. R2 (register pipeline) and R3 (chunked LDS)
//   both capped at ~2.6 TB/s combined memory service — the shared trait was
//   strided row-slice reads (640B every 3136B). A block's image rows are
//   CONTIGUOUS in memory, so staging the FULL slab (all K at once) makes the
//   global reads two perfectly linear 25KB streams (1KB contiguous per wave
//   instruction — the 6.3TB/s copy-bench pattern). 8 pairs/block, 16-row bf16
//   LDS slab (a rows 0-7, b rows 8-15), 6 blocks/CU (24 waves/CU). Compute:
//   4 waves N-split H=64; per K-step 1 ds_read_b128 + 1 L2 w1s load + 1 MFMA.
// =============================================================================

#define KDIM   784
#define HDIM   64
#define KSTEPS 25                        // ceil(784/32); w1s zero-padded to 800
#define W1S_ELEMS (KSTEPS * 4 * 64 * 8)  // 51200 bf16 in B-fragment order
#define W1S_BYTES (W1S_ELEMS * 2)        // 102400 bytes

#define PAIRS  8                         // pairs per block
#define ROWQ   196                       // f32x4 quads per image row (784/4)
#define SLABQ  (PAIRS * ROWQ)            // 1568 quads per slab (25,088 B)
#define TOTQ   (2 * SLABQ)               // 3136 quads (a + b)
#define LSTR   792                       // LDS row stride in shorts: 1584 B =
                                         // 16*99 (16B-aligned, odd*16B -> uniform banks)

typedef float  f32x4  __attribute__((ext_vector_type(4)));
typedef short  bf16x8 __attribute__((ext_vector_type(8)));

__device__ __forceinline__ unsigned short f2bf(float f) {
  unsigned u = __float_as_uint(f);
  u += 0x7fffu + ((u >> 16) & 1u);       // round-to-nearest-even
  return (unsigned short)(u >> 16);
}

__device__ __forceinline__ float bf2f(unsigned short h) {
  return __uint_as_float(((unsigned)h) << 16);
}

__device__ __forceinline__ uint2 cvt4(f32x4 v) {
  uint2 r;
  r.x = ((unsigned)f2bf(v[0])) | (((unsigned)f2bf(v[1])) << 16);
  r.y = ((unsigned)f2bf(v[2])) | (((unsigned)f2bf(v[3])) << 16);
  return r;
}

__device__ __forceinline__ float tanh_fast(float x) {
  float e = __expf(2.0f * x);
  return 1.0f - 2.0f / (e + 1.0f);       // exact limits at +-inf
}

// --- prep: W1 (784x64 f32) -> bf16 in MFMA B-fragment order, K padded to 800;
//           W2 (64x16) -> transposed (16x64) f32.  (unchanged)
__global__ __launch_bounds__(256)
void prep_kernel(const float* __restrict__ W1, const float* __restrict__ W2,
                 unsigned short* __restrict__ w1s, float* __restrict__ w2t) {
  int tid = blockIdx.x * 256 + threadIdx.x;
  if (tid < W1S_ELEMS) {
    int j  = tid & 7;            // element within 8-wide fragment
    int l  = (tid >> 3) & 63;    // lane
    int st = tid >> 9;           // s*4 + t
    int s  = st >> 2;
    int t  = st & 3;
    int k  = s * 32 + (l >> 4) * 8 + j;   // B[k][n]: k = quad*8+j
    int n  = t * 16 + (l & 15);           //          n = lane&15
    float v = (k < KDIM) ? W1[k * HDIM + n] : 0.0f;
    w1s[tid] = f2bf(v);
  }
  if (tid < HDIM * 16) {
    int c = tid >> 6;            // 0..15
    int k = tid & 63;            // 0..63
    w2t[c * HDIM + k] = W2[k * 16 + c];
  }
}

// per-staging-element address map: flat quad index i over [img_a slab][img_b slab]
struct StElem { const float* src; int lrow; int lkq; };
__device__ __forceinline__ StElem staddr(int i, const float* a, const float* b,
                                         int p0) {
  int sl  = (i >= SLABQ);
  int j   = i - (sl ? SLABQ : 0);
  int row = j / ROWQ;                  // constant div -> magic mul
  int kq  = j - row * ROWQ;
  StElem e;
  e.src  = (sl ? b : a) + (size_t)(p0 + row) * KDIM + (size_t)kq * 4;
  e.lrow = sl * PAIRS + row;           // a: rows 0-7, b: rows 8-15
  e.lkq  = kq;
  return e;
}

// --- main: 8 pairs/block, 256 threads, 6 blocks/CU.
__global__ __launch_bounds__(256, 6)
void qcm_kernel(const float* __restrict__ img_a, const float* __restrict__ img_b,
                const float* __restrict__ b1,    const float* __restrict__ b2,
                const unsigned short* __restrict__ w1s,
                const float* __restrict__ w2t,
                float* __restrict__ out) {
  __shared__ __attribute__((aligned(16))) unsigned short lds_s[16][LSTR]; // 25,344 B

  const int tid  = threadIdx.x;
  const int lane = tid & 63;
  const int wv   = tid >> 6;      // wave id = N-tile (cols wv*16..wv*16+15)
  const int m    = lane & 15;
  const int q    = lane >> 4;
  const int p0   = blockIdx.x * PAIRS;

  // ---- staging: two linear streams (25 KB each), 12 quads/thread + tail.
  //      Global addrs are linear in i (rows contiguous): 1KB/wave-instr bursts.
  {
    f32x4 v0[6], v1[6], vt;
    #pragma unroll
    for (int r = 0; r < 6; ++r) {
      StElem e = staddr(tid + 256 * r, img_a, img_b, p0);
      v0[r] = *(const f32x4*)e.src;
    }
    #pragma unroll
    for (int r = 6; r < 12; ++r) {
      StElem e = staddr(tid + 256 * r, img_a, img_b, p0);
      v1[r - 6] = *(const f32x4*)e.src;
    }
    const bool tl = tid < (TOTQ - 12 * 256);   // 64 tail quads
    if (tl) {
      StElem e = staddr(tid + 3072, img_a, img_b, p0);
      vt = *(const f32x4*)e.src;
    }
    #pragma unroll
    for (int r = 0; r < 6; ++r) {
      StElem e = staddr(tid + 256 * r, img_a, img_b, p0);
      *(uint2*)&lds_s[e.lrow][e.lkq * 4] = cvt4(v0[r]);
    }
    #pragma unroll
    for (int r = 6; r < 12; ++r) {
      StElem e = staddr(tid + 256 * r, img_a, img_b, p0);
      *(uint2*)&lds_s[e.lrow][e.lkq * 4] = cvt4(v1[r - 6]);
    }
    if (tl) {
      StElem e = staddr(tid + 3072, img_a, img_b, p0);
      *(uint2*)&lds_s[e.lrow][e.lkq * 4] = cvt4(vt);
    }
  }
  __syncthreads();

  // ---- compute: wave wv owns output cols wv*16..+15 for all 16 rows.
  //      A-frag row m = LDS row (0-7 = a-pairs, 8-15 = b-pairs), k = s*32+q*8.
  const int4* bw = (const int4*)w1s + wv * 64 + lane;
  f32x4 acc; acc[0] = acc[1] = acc[2] = acc[3] = 0.0f;
  const unsigned short* arow = &lds_s[m][q * 8];

  int4 g0 = bw[0];
  int4 g1 = bw[256];
  #pragma unroll
  for (int s = 0; s < KSTEPS; ++s) {
    int4 g = (s & 1) ? g1 : g0;
    if (s + 2 < KSTEPS) {                       // depth-2 w1s prefetch (L2)
      if (s & 1) g1 = bw[(s + 2) * 256];
      else       g0 = bw[(s + 2) * 256];
    }
    bf16x8 fa = *(const bf16x8*)(arow + s * 32);
    if (s == KSTEPS - 1 && q >= 2) {
      // k >= 784: LDS garbage; w1s is zero there but 0*NaN != 0 — zero A.
      #pragma unroll
      for (int e = 0; e < 8; ++e) fa[e] = 0;
    }
    acc = __builtin_amdgcn_mfma_f32_16x16x32_bf16(
        fa, __builtin_bit_cast(bf16x8, g), acc, 0, 0, 0);
  }

  // ---- epilogue: bias + relu, park h bf16 over the (dead) staging LDS.
  //      D: row = q*4+j (0-7 a-pair r, 8-15 b-pair r-8), col = wv*16+m.
  __syncthreads();                               // all waves done reading lds_s
  unsigned short (*lds_h)[72] = (unsigned short (*)[72])&lds_s[0][0];
  {
    float bias = b1[wv * 16 + m];
    #pragma unroll
    for (int j = 0; j < 4; ++j) {
      int r = q * 4 + j;
      float hv = fmaxf(acc[j] + bias, 0.0f);
      lds_h[r][wv * 16 + m] = f2bf(hv);
    }
  }
  __syncthreads();

  // ---- phase 2: 32 threads/pair; thread = (col c, k-half hf) of its pair.
  const int p  = tid >> 5;                       // local pair 0..7
  const int c  = tid & 15;
  const int hf = (tid >> 4) & 1;
  const unsigned short* ha = &lds_h[p][hf * 32];
  const unsigned short* hb = &lds_h[8 + p][hf * 32];

  float za = 0.0f, zb = 0.0f;
  #pragma unroll
  for (int k = 0; k < 32; k += 4) {
    uint2 ua = *(const uint2*)(ha + k);
    uint2 ub = *(const uint2*)(hb + k);
    f32x4 wvv = *(const f32x4*)(w2t + c * HDIM + hf * 32 + k);
    za += bf2f((unsigned short)(ua.x & 0xffff)) * wvv[0]
        + bf2f((unsigned short)(ua.x >> 16))    * wvv[1]
        + bf2f((unsigned short)(ua.y & 0xffff)) * wvv[2]
        + bf2f((unsigned short)(ua.y >> 16))    * wvv[3];
    zb += bf2f((unsigned short)(ub.x & 0xffff)) * wvv[0]
        + bf2f((unsigned short)(ub.x >> 16))    * wvv[1]
        + bf2f((unsigned short)(ub.y & 0xffff)) * wvv[2]
        + bf2f((unsigned short)(ub.y >> 16))    * wvv[3];
  }
  za += __shfl_xor(za, 16);                      // combine k-halves
  zb += __shfl_xor(zb, 16);
  za += b2[c];
  zb += b2[c];

  float uaf = tanh_fast(za);
  float ubf = tanh_fast(zb);
  float d = uaf * ubf, na2 = uaf * uaf, nb2 = ubf * ubf;
  d   += __shfl_xor(d, 1);   d   += __shfl_xor(d, 2);
  d   += __shfl_xor(d, 4);   d   += __shfl_xor(d, 8);
  na2 += __shfl_xor(na2, 1); na2 += __shfl_xor(na2, 2);
  na2 += __shfl_xor(na2, 4); na2 += __shfl_xor(na2, 8);
  nb2 += __shfl_xor(nb2, 1); nb2 += __shfl_xor(nb2, 2);
  nb2 += __shfl_xor(nb2, 4); nb2 += __shfl_xor(nb2, 8);

  if ((tid & 31) == 0) {
    float den = fmaxf(sqrtf(na2), 1e-8f) * fmaxf(sqrtf(nb2), 1e-8f);
    float ov  = d / den;
    float fid = ov * ov;
    out[p0 + p] = fminf(fid, 1.0f);
  }
}

extern "C" void kernel_launch(void* const* d_in, const int* in_sizes, int n_in,
                              void* d_out, int out_size, void* d_ws, size_t ws_size,
                              hipStream_t stream) {
  const float* img_a = (const float*)d_in[0];
  const float* img_b = (const float*)d_in[1];
  const float* W1    = (const float*)d_in[2];
  const float* b1    = (const float*)d_in[3];
  const float* W2    = (const float*)d_in[4];
  const float* b2    = (const float*)d_in[5];
  // d_in[6] = theta: unused — the circuit is unitary, fidelity is invariant.

  unsigned short* w1s = (unsigned short*)d_ws;
  float* w2t = (float*)((char*)d_ws + W1S_BYTES);

  prep_kernel<<<(W1S_ELEMS + 255) / 256, 256, 0, stream>>>(W1, W2, w1s, w2t);

  const int n_pairs = out_size;              // 65536
  qcm_kernel<<<n_pairs / PAIRS, 256, 0, stream>>>(img_a, img_b, b1, b2,
                                                  w1s, w2t, (float*)d_out);
}